// Round 6
// baseline (5392.036 us; speedup 1.0000x reference)
//
#include <hip/hip_runtime.h>
#include <hip/hip_bf16.h>

#define L_SEQ 1024
#define D_MODEL 768
#define D_INNER 1536
#define D_STATE 16
#define DT_RANK 48
#define N_LAYERS 24
#define NCHUNK 16
#define CS (L_SEQ / NCHUNK)  // 64

typedef __attribute__((ext_vector_type(8))) short short8;
typedef __attribute__((ext_vector_type(4))) float f32x4;

__device__ inline void split1(float v, ushort& hi, ushort& lo) {
  unsigned b = __float_as_uint(v);
  hi = (ushort)(b >> 16);
  float lof = v - __uint_as_float(b & 0xFFFF0000u);
  lo = (ushort)(__float_as_uint(lof) >> 16);
}

__device__ inline void gload16(const void* g, void* l) {
  __builtin_amdgcn_global_load_lds(
      (const __attribute__((address_space(1))) void*)g,
      (__attribute__((address_space(3))) void*)l, 16, 0, 0);
}

// ---------------------------------------------------------------------------
// transpose + split: in [K][N] fp32 (layer l) -> hi/lo [N][Kp] bf16.
// rows k >= K zero-padded. grid (N/64, Kp/64, L) x 256.
__global__ __launch_bounds__(256) void tsplit_k(
    const float* __restrict__ in, ushort* __restrict__ hi,
    ushort* __restrict__ lo, int K, int N, int Kp) {
  __shared__ float tile[64][65];
  const int l = blockIdx.z;
  const float* src = in + (size_t)l * K * N;
  ushort* dh = hi + (size_t)l * N * Kp;
  ushort* dl = lo + (size_t)l * N * Kp;
  const int n0 = blockIdx.x * 64, k0 = blockIdx.y * 64;
  const int tx = threadIdx.x & 63, ty = threadIdx.x >> 6;
#pragma unroll
  for (int rr = 0; rr < 16; rr++) {
    int ky = rr * 4 + ty;
    int k = k0 + ky;
    tile[ky][tx] = (k < K) ? src[(size_t)k * N + n0 + tx] : 0.f;
  }
  __syncthreads();
#pragma unroll
  for (int rr = 0; rr < 16; rr++) {
    int ny = rr * 4 + ty;
    float v = tile[tx][ny];
    ushort h, s;
    split1(v, h, s);
    size_t o = (size_t)(n0 + ny) * Kp + k0 + tx;
    dh[o] = h;
    dl[o] = s;
  }
}

// ---------------------------------------------------------------------------
// split-bf16 3-pass MFMA GEMM, pre-split inputs, global_load_lds staging.
// A: hi/lo [M][lda] bf16, B: hi/lo [N][ldb] bf16 (transposed weights).
// C fp32 [M][ldc]. K % 32 == 0, M % 128 == 0, N % BN == 0.
// block = 512 thr = 8 waves (2 x 4); BM=128, BK=32.
// LDS row space: [Ahi(BM) | Alo(BM) | Bhi(BN) | Blo(BN)] x 32 bf16 cols,
// staged as 1 KB wave-segments (16 rows each) by global_load_lds width 16.
// EPI: 0 = store, 1 = softplus(c + bias[n]), 2 = C += c
template <int BN, int EPI>
__global__ __launch_bounds__(512) void gemm_bf16s(
    const ushort* __restrict__ Ahi, const ushort* __restrict__ Alo, int lda,
    const ushort* __restrict__ Bhi, const ushort* __restrict__ Blo, int ldb,
    float* __restrict__ C, int ldc, int K, const float* __restrict__ bias) {
  constexpr int BM = 128;
  constexpr int BNF = BN / 64;               // B frags per wave (wave cols/16)
  constexpr int NSEG = (2 * BM + 2 * BN) / 16;  // 1 KB segments per K-step
  __shared__ ushort lds[(2 * BM + 2 * BN) * 32];

  const int tid = threadIdx.x;
  const int bm = blockIdx.y * BM;
  const int bn = blockIdx.x * BN;
  const int lane = tid & 63;
  const int wid = tid >> 6;        // 0..7
  const int wm = wid & 1;          // 2 wave-rows (64 rows each)
  const int wn = wid >> 1;         // 4 wave-cols (BN/4 cols each)
  const int r = lane & 15, g = lane >> 4;
  const int segrow = lane >> 2, segch = lane & 3;  // staging within segment

  f32x4 acc[4][BNF] = {};

  for (int k0 = 0; k0 < K; k0 += 32) {
    // ---- issue async global->LDS staging for this K-step
    for (int s = wid; s < NSEG; s += 8) {
      int gr = s * 16 + segrow;
      const ushort* src;
      int row, ld;
      if (gr < BM) {
        src = Ahi; row = bm + gr; ld = lda;
      } else if (gr < 2 * BM) {
        src = Alo; row = bm + gr - BM; ld = lda;
      } else if (gr < 2 * BM + BN) {
        src = Bhi; row = bn + gr - 2 * BM; ld = ldb;
      } else {
        src = Blo; row = bn + gr - 2 * BM - BN; ld = ldb;
      }
      gload16(src + (size_t)row * ld + k0 + segch * 8, &lds[s * 512]);
    }
    __syncthreads();  // drains vmcnt -> LDS tiles ready

    short8 ahi[4], alo[4], bhi[BNF], blo[BNF];
#pragma unroll
    for (int m = 0; m < 4; m++) {
      int row = wm * 64 + m * 16 + r;
      ahi[m] = *reinterpret_cast<short8*>(&lds[row * 32 + g * 8]);
      alo[m] = *reinterpret_cast<short8*>(&lds[BM * 32 + row * 32 + g * 8]);
    }
#pragma unroll
    for (int n = 0; n < BNF; n++) {
      int row = wn * (BN / 4) + n * 16 + r;
      bhi[n] = *reinterpret_cast<short8*>(&lds[2 * BM * 32 + row * 32 + g * 8]);
      blo[n] = *reinterpret_cast<short8*>(
          &lds[(2 * BM + BN) * 32 + row * 32 + g * 8]);
    }
#pragma unroll
    for (int m = 0; m < 4; m++)
#pragma unroll
      for (int n = 0; n < BNF; n++) {
        acc[m][n] = __builtin_amdgcn_mfma_f32_16x16x32_bf16(
            ahi[m], bhi[n], acc[m][n], 0, 0, 0);
        acc[m][n] = __builtin_amdgcn_mfma_f32_16x16x32_bf16(
            ahi[m], blo[n], acc[m][n], 0, 0, 0);
        acc[m][n] = __builtin_amdgcn_mfma_f32_16x16x32_bf16(
            alo[m], bhi[n], acc[m][n], 0, 0, 0);
      }
    __syncthreads();  // all reads done before next staging overwrites
  }

#pragma unroll
  for (int m = 0; m < 4; m++) {
#pragma unroll
    for (int n = 0; n < BNF; n++) {
      int row0 = bm + wm * 64 + m * 16 + g * 4;
      int col = bn + wn * (BN / 4) + n * 16 + r;
#pragma unroll
      for (int j = 0; j < 4; j++) {
        size_t idx = (size_t)(row0 + j) * ldc + col;
        float v = acc[m][n][j];
        if (EPI == 0) {
          C[idx] = v;
        } else if (EPI == 1) {
          v += bias[col];
          C[idx] = (v > 20.f) ? v : log1pf(__expf(v));
        } else {
          C[idx] += v;
        }
      }
    }
  }
}

// ---------------------------------------------------------------------------
__global__ __launch_bounds__(256) void encode_k(
    const float* __restrict__ x, const float* __restrict__ w_enc,
    const float* __restrict__ b_enc, float* __restrict__ u) {
  int d = blockIdx.x * 256 + threadIdx.x;
  int t = blockIdx.y;
  const float4 xv = *(const float4*)(x + t * 4);
  float acc = b_enc[d];
  acc = fmaf(xv.x, w_enc[0 * D_MODEL + d], acc);
  acc = fmaf(xv.y, w_enc[1 * D_MODEL + d], acc);
  acc = fmaf(xv.z, w_enc[2 * D_MODEL + d], acc);
  acc = fmaf(xv.w, w_enc[3 * D_MODEL + d], acc);
  u[t * D_MODEL + d] = acc;
}

// ---------------------------------------------------------------------------
// rmsnorm with split-bf16 output planes
__global__ __launch_bounds__(256) void rmsnorm_split_k(
    const float* __restrict__ u, const float* __restrict__ w,
    ushort* __restrict__ hh, ushort* __restrict__ hl) {
  int t = blockIdx.x;
  const float* ur = u + t * D_MODEL;
  float ss = 0.f;
  for (int d = threadIdx.x; d < D_MODEL; d += 256) {
    float v = ur[d];
    ss = fmaf(v, v, ss);
  }
#pragma unroll
  for (int o = 1; o < 64; o <<= 1) ss += __shfl_xor(ss, o);
  __shared__ float red[4];
  int wid = threadIdx.x >> 6;
  if ((threadIdx.x & 63) == 0) red[wid] = ss;
  __syncthreads();
  float tot = red[0] + red[1] + red[2] + red[3];
  float rs = rsqrtf(tot / (float)D_MODEL + 1e-5f);
  for (int d = threadIdx.x; d < D_MODEL; d += 256) {
    float v = ur[d] * rs * w[d];
    ushort h, s;
    split1(v, h, s);
    hh[t * D_MODEL + d] = h;
    hl[t * D_MODEL + d] = s;
  }
}

// ---------------------------------------------------------------------------
// dbl GEMM (M=1024, N=80, K=1536) split-K partial kernel (fp32).
#define DBL_NS 8
#define DBL_KSEG (D_INNER / DBL_NS)  // 192
__global__ __launch_bounds__(256) void gemm_dbl_k(
    const float* __restrict__ A, const float* __restrict__ B,
    float* __restrict__ P) {
  __shared__ float As2[16][17];
  __shared__ float Bs2[16][80];
  const int tid = threadIdx.x;
  const int bm = blockIdx.y * 16;
  const int ks0 = blockIdx.x * DBL_KSEG;
  const int tx = tid % 16;
  const int ty = tid / 16;

  float acc[5] = {0.f, 0.f, 0.f, 0.f, 0.f};

  for (int k0 = ks0; k0 < ks0 + DBL_KSEG; k0 += 16) {
    {
      int m = tid / 16, k = tid % 16;
      As2[k][m] = A[(size_t)(bm + m) * D_INNER + k0 + k];
    }
    for (int i = tid; i < 16 * 80; i += 256) {
      int k = i / 80, n = i % 80;
      Bs2[k][n] = B[(size_t)(k0 + k) * 80 + n];
    }
    __syncthreads();
#pragma unroll
    for (int k = 0; k < 16; k++) {
      float ra = As2[k][ty];
#pragma unroll
      for (int j = 0; j < 5; j++) acc[j] = fmaf(ra, Bs2[k][tx * 5 + j], acc[j]);
    }
    __syncthreads();
  }

  float* p = P + ((size_t)blockIdx.x * L_SEQ + bm + ty) * 80 + tx * 5;
#pragma unroll
  for (int j = 0; j < 5; j++) p[j] = acc[j];
}

// reduce + emit dtA split planes [1024][64] (cols 48..63 zero)
__global__ __launch_bounds__(256) void dbl_reduce_k(
    const float* __restrict__ P, float* __restrict__ dbl,
    ushort* __restrict__ dah, ushort* __restrict__ dal) {
  int i = blockIdx.x * 256 + threadIdx.x;  // 0..81919
  float s = 0.f;
#pragma unroll
  for (int ks = 0; ks < DBL_NS; ks++) s += P[(size_t)ks * L_SEQ * 80 + i];
  dbl[i] = s;
  int rowi = i / 80, col = i % 80;
  if (col < DT_RANK) {
    ushort h, lo;
    split1(s, h, lo);
    dah[rowi * 64 + col] = h;
    dal[rowi * 64 + col] = lo;
  } else if (col >= 64) {  // cover pad cols 48..63
    dah[rowi * 64 + col - 16] = 0;
    dal[rowi * 64 + col - 16] = 0;
  }
}

// ---------------------------------------------------------------------------
__global__ __launch_bounds__(256) void conv_silu_k(
    const float* __restrict__ xz, const float* __restrict__ cw,
    const float* __restrict__ cb, float* __restrict__ xc) {
  int c = blockIdx.x * 256 + threadIdx.x;
  int t = blockIdx.y;
  const float4 w = *(const float4*)(cw + c * 4);
  float acc = cb[c];
  if (t - 3 >= 0) acc = fmaf(xz[(t - 3) * 2 * D_INNER + c], w.x, acc);
  if (t - 2 >= 0) acc = fmaf(xz[(t - 2) * 2 * D_INNER + c], w.y, acc);
  if (t - 1 >= 0) acc = fmaf(xz[(t - 1) * 2 * D_INNER + c], w.z, acc);
  acc = fmaf(xz[t * 2 * D_INNER + c], w.w, acc);
  xc[t * D_INNER + c] = acc / (1.f + __expf(-acc));
}

// ---------------------------------------------------------------------------
// Chunked selective scan (3 phases), NCHUNK=16 chunks of 64 steps.
__global__ __launch_bounds__(256) void scan1_k(
    const float* __restrict__ dt, const float* __restrict__ xc,
    const float* __restrict__ dbl, const float* __restrict__ A_log,
    float* __restrict__ Pb, float* __restrict__ Eb) {
  __shared__ float s_dt[CS][16];
  __shared__ float s_xc[CS][16];
  __shared__ float s_b[CS][16];
  const int tid = threadIdx.x;
  const int s = tid & 15;
  const int cl = tid >> 4;
  const int c0 = blockIdx.y * 16;
  const int c = c0 + cl;
  const int t0 = blockIdx.x * CS;
  const float a = -__expf(A_log[c * D_STATE + s]);

  const int lc = tid & 15, lt = tid >> 4;
#pragma unroll
  for (int p = 0; p < CS / 16; p++) {
    int t = lt + p * 16;
    size_t gt = (size_t)(t0 + t);
    s_dt[t][lc] = dt[gt * D_INNER + c0 + lc];
    s_xc[t][lc] = xc[gt * D_INNER + c0 + lc];
    s_b[t][lc] = dbl[gt * 80 + DT_RANK + lc];
  }
  __syncthreads();

  float P = 1.f, h = 0.f;
  for (int t = 0; t < CS; t++) {
    float dtv = s_dt[t][cl];
    float dA = __expf(dtv * a);
    P *= dA;
    h = fmaf(dA, h, dtv * s_b[t][s] * s_xc[t][cl]);
  }
  int idx = blockIdx.x * (D_INNER * D_STATE) + c0 * D_STATE + tid;
  Pb[idx] = P;
  Eb[idx] = h;
}

__global__ __launch_bounds__(256) void scan2_k(
    const float* __restrict__ Pb, const float* __restrict__ Eb,
    float* __restrict__ Hb) {
  int i = blockIdx.x * 256 + threadIdx.x;
  float H = 0.f;
#pragma unroll
  for (int j = 0; j < NCHUNK; j++) {
    int o = j * (D_INNER * D_STATE) + i;
    Hb[o] = H;
    H = fmaf(Pb[o], H, Eb[o]);
  }
}

// phase 3 -> writes y as split bf16 planes (feeds out-proj GEMM)
__global__ __launch_bounds__(256) void scan3_k(
    const float* __restrict__ dt, const float* __restrict__ xc,
    const float* __restrict__ dbl, const float* __restrict__ xz,
    const float* __restrict__ A_log, const float* __restrict__ D_skip,
    const float* __restrict__ Hb, ushort* __restrict__ yh,
    ushort* __restrict__ yl) {
  __shared__ float s_dt[CS][16];
  __shared__ float s_xc[CS][16];
  __shared__ float s_z[CS][16];
  __shared__ float s_bc[CS][32];

  const int tid = threadIdx.x;
  const int s = tid & 15;
  const int cl = tid >> 4;
  const int c0 = blockIdx.y * 16;
  const int c = c0 + cl;
  const int t0 = blockIdx.x * CS;

  const float a = -__expf(A_log[c * D_STATE + s]);
  const float Dv = D_skip[c];

  const int lc = tid & 15, lt = tid >> 4;
  const int bj = tid & 31, bt = tid >> 5;
#pragma unroll
  for (int p = 0; p < CS / 16; p++) {
    int t = lt + p * 16;
    size_t gt = (size_t)(t0 + t);
    s_dt[t][lc] = dt[gt * D_INNER + c0 + lc];
    s_xc[t][lc] = xc[gt * D_INNER + c0 + lc];
    s_z[t][lc] = xz[gt * 2 * D_INNER + D_INNER + c0 + lc];
  }
#pragma unroll
  for (int p = 0; p < CS / 8; p++) {
    int t = bt + p * 8;
    s_bc[t][bj] = dbl[(size_t)(t0 + t) * 80 + DT_RANK + bj];
  }
  __syncthreads();

  float hst = Hb[blockIdx.x * (D_INNER * D_STATE) + c0 * D_STATE + tid];

  for (int t = 0; t < CS; t++) {
    float dtv = s_dt[t][cl];
    float xv = s_xc[t][cl];
    float Bv = s_bc[t][s];
    float Cv = s_bc[t][16 + s];
    float dA = __expf(dtv * a);
    hst = fmaf(dA, hst, dtv * Bv * xv);
    float p2 = hst * Cv;
    p2 += __shfl_xor(p2, 1);
    p2 += __shfl_xor(p2, 2);
    p2 += __shfl_xor(p2, 4);
    p2 += __shfl_xor(p2, 8);
    if (s == 0) {
      float zv = s_z[t][cl];
      float sz = zv / (1.f + __expf(-zv));
      float yv = (p2 + Dv * xv) * sz;
      ushort h, lo;
      split1(yv, h, lo);
      size_t o = (size_t)(t0 + t) * D_INNER + c;
      yh[o] = h;
      yl[o] = lo;
    }
  }
}

// ---------------------------------------------------------------------------
__global__ __launch_bounds__(256) void final_k(
    const float* __restrict__ u, const float* __restrict__ nfw,
    const float* __restrict__ fcw, const float* __restrict__ fcb,
    float* __restrict__ out) {
  const float* ur = u + (size_t)(L_SEQ - 1) * D_MODEL;
  float ss = 0.f;
  for (int d = threadIdx.x; d < D_MODEL; d += 256) {
    float v = ur[d];
    ss = fmaf(v, v, ss);
  }
#pragma unroll
  for (int o = 1; o < 64; o <<= 1) ss += __shfl_xor(ss, o);
  __shared__ float red[4];
  int wid = threadIdx.x >> 6;
  if ((threadIdx.x & 63) == 0) red[wid] = ss;
  __syncthreads();
  float tot = red[0] + red[1] + red[2] + red[3];
  float rs = rsqrtf(tot / (float)D_MODEL + 1e-5f);
  float a0 = 0.f, a1 = 0.f;
  for (int d = threadIdx.x; d < D_MODEL; d += 256) {
    float hn = ur[d] * rs * nfw[d];
    a0 = fmaf(hn, fcw[d * 2 + 0], a0);
    a1 = fmaf(hn, fcw[d * 2 + 1], a1);
  }
#pragma unroll
  for (int o = 1; o < 64; o <<= 1) {
    a0 += __shfl_xor(a0, o);
    a1 += __shfl_xor(a1, o);
  }
  __shared__ float r0[4], r1[4];
  if ((threadIdx.x & 63) == 0) {
    r0[wid] = a0;
    r1[wid] = a1;
  }
  __syncthreads();
  if (threadIdx.x == 0) out[0] = r0[0] + r0[1] + r0[2] + r0[3] + fcb[0];
  if (threadIdx.x == 1) out[1] = r1[0] + r1[1] + r1[2] + r1[3] + fcb[1];
}

// ---------------------------------------------------------------------------
extern "C" void kernel_launch(void* const* d_in, const int* in_sizes, int n_in,
                              void* d_out, int out_size, void* d_ws,
                              size_t ws_size, hipStream_t stream) {
  const float* x      = (const float*)d_in[0];
  const float* w_enc  = (const float*)d_in[1];
  const float* b_enc  = (const float*)d_in[2];
  const float* norm_w = (const float*)d_in[3];
  const float* in_w   = (const float*)d_in[4];
  const float* conv_w = (const float*)d_in[5];
  const float* conv_b = (const float*)d_in[6];
  const float* xp_w   = (const float*)d_in[7];
  const float* dt_w   = (const float*)d_in[8];
  const float* dt_b   = (const float*)d_in[9];
  const float* A_log  = (const float*)d_in[10];
  const float* D_skip = (const float*)d_in[11];
  const float* out_w  = (const float*)d_in[12];
  const float* nf_w   = (const float*)d_in[13];
  const float* fc_w   = (const float*)d_in[14];
  const float* fc_b   = (const float*)d_in[15];
  float* out = (float*)d_out;

  // ---- fp32 workspace
  float* u   = (float*)d_ws;
  float* xzb = u   + (size_t)L_SEQ * D_MODEL;
  float* xcb = xzb + (size_t)L_SEQ * 2 * D_INNER;
  float* dbl = xcb + (size_t)L_SEQ * D_INNER;
  float* dtb = dbl + (size_t)L_SEQ * 80;
  float* yb  = dtb + (size_t)L_SEQ * D_INNER;   // dbl split-K partials
  float* Pb  = yb  + (size_t)L_SEQ * D_INNER;
  float* Eb  = Pb  + (size_t)NCHUNK * D_INNER * D_STATE;
  float* Hb  = Eb  + (size_t)NCHUNK * D_INNER * D_STATE;
  float* fend = Hb + (size_t)NCHUNK * D_INNER * D_STATE;

  // ---- bf16 plane workspace (activations + repacked weights)
  ushort* hh  = (ushort*)fend;                  // [1024][768]
  ushort* hl  = hh + (size_t)L_SEQ * D_MODEL;
  ushort* dah = hl + (size_t)L_SEQ * D_MODEL;   // [1024][64]
  ushort* dal = dah + (size_t)L_SEQ * 64;
  ushort* yh  = dal + (size_t)L_SEQ * 64;       // [1024][1536]
  ushort* yl  = yh + (size_t)L_SEQ * D_INNER;
  ushort* wxh = yl + (size_t)L_SEQ * D_INNER;   // in_w^T  [24][3072][768]
  ushort* wxl = wxh + (size_t)N_LAYERS * 2 * D_INNER * D_MODEL;
  ushort* wdh = wxl + (size_t)N_LAYERS * 2 * D_INNER * D_MODEL;  // dt_w^T [24][1536][64]
  ushort* wdl = wdh + (size_t)N_LAYERS * D_INNER * 64;
  ushort* woh = wdl + (size_t)N_LAYERS * D_INNER * 64;  // out_w^T [24][768][1536]
  ushort* wol = woh + (size_t)N_LAYERS * D_MODEL * D_INNER;

  // ---- one-time per call: weight repack (transpose + bf16 split)
  tsplit_k<<<dim3(2 * D_INNER / 64, D_MODEL / 64, N_LAYERS), 256, 0, stream>>>(
      in_w, wxh, wxl, D_MODEL, 2 * D_INNER, D_MODEL);
  tsplit_k<<<dim3(D_INNER / 64, 1, N_LAYERS), 256, 0, stream>>>(
      dt_w, wdh, wdl, DT_RANK, D_INNER, 64);
  tsplit_k<<<dim3(D_MODEL / 64, D_INNER / 64, N_LAYERS), 256, 0, stream>>>(
      out_w, woh, wol, D_INNER, D_MODEL, D_INNER);

  encode_k<<<dim3(3, L_SEQ), 256, 0, stream>>>(x, w_enc, b_enc, u);

  for (int l = 0; l < N_LAYERS; l++) {
    const float* cw_l    = conv_w + (size_t)l * D_INNER * 4;
    const float* cb_l    = conv_b + (size_t)l * D_INNER;
    const float* xp_w_l  = xp_w  + (size_t)l * D_INNER * 80;
    const float* dt_b_l  = dt_b  + (size_t)l * D_INNER;
    const float* A_log_l = A_log + (size_t)l * D_INNER * D_STATE;
    const float* D_l     = D_skip + (size_t)l * D_INNER;
    const ushort* wxh_l = wxh + (size_t)l * 2 * D_INNER * D_MODEL;
    const ushort* wxl_l = wxl + (size_t)l * 2 * D_INNER * D_MODEL;
    const ushort* wdh_l = wdh + (size_t)l * D_INNER * 64;
    const ushort* wdl_l = wdl + (size_t)l * D_INNER * 64;
    const ushort* woh_l = woh + (size_t)l * D_MODEL * D_INNER;
    const ushort* wol_l = wol + (size_t)l * D_MODEL * D_INNER;

    // h(hi/lo) = rmsnorm(u) * norm_w
    rmsnorm_split_k<<<L_SEQ, 256, 0, stream>>>(
        u, norm_w + (size_t)l * D_MODEL, hh, hl);
    // xz = h @ in_w : M=1024 N=3072 K=768
    gemm_bf16s<128, 0><<<dim3(2 * D_INNER / 128, L_SEQ / 128), 512, 0, stream>>>(
        hh, hl, D_MODEL, wxh_l, wxl_l, D_MODEL, xzb, 2 * D_INNER, D_MODEL,
        nullptr);
    // xc = silu(conv(xpart) + cb)
    conv_silu_k<<<dim3(6, L_SEQ), 256, 0, stream>>>(xzb, cw_l, cb_l, xcb);
    // dbl = xc @ xp_w : M=1024 N=80 K=1536 (split-K x8 + reduce, fp32)
    gemm_dbl_k<<<dim3(DBL_NS, L_SEQ / 16), 256, 0, stream>>>(xcb, xp_w_l, yb);
    dbl_reduce_k<<<(L_SEQ * 80) / 256, 256, 0, stream>>>(yb, dbl, dah, dal);
    // dt = softplus(dbl[:, :48] @ dt_w + dt_b) : K=48 padded to 64
    gemm_bf16s<128, 1><<<dim3(D_INNER / 128, L_SEQ / 128), 512, 0, stream>>>(
        dah, dal, 64, wdh_l, wdl_l, 64, dtb, D_INNER, 64, dt_b_l);
    // chunked selective scan + skip + silu(z) gate -> y (split planes)
    scan1_k<<<dim3(NCHUNK, D_INNER / 16), 256, 0, stream>>>(
        dtb, xcb, dbl, A_log_l, Pb, Eb);
    scan2_k<<<(D_INNER * D_STATE) / 256, 256, 0, stream>>>(Pb, Eb, Hb);
    scan3_k<<<dim3(NCHUNK, D_INNER / 16), 256, 0, stream>>>(
        dtb, xcb, dbl, xzb, A_log_l, D_l, Hb, yh, yl);
    // u += y @ out_w : M=1024 N=768 K=1536 (BN=64 -> 96 blocks)
    gemm_bf16s<64, 2><<<dim3(D_MODEL / 64, L_SEQ / 128), 512, 0, stream>>>(
        yh, yl, D_INNER, woh_l, wol_l, D_INNER, u, D_MODEL, D_INNER, nullptr);
  }

  final_k<<<1, 256, 0, stream>>>(u, nf_w, fc_w, fc_b, out);
}

// Round 7
// 4308.522 us; speedup vs baseline: 1.2515x; 1.2515x over previous
//
#include <hip/hip_runtime.h>
#include <hip/hip_bf16.h>

#define L_SEQ 1024
#define D_MODEL 768
#define D_INNER 1536
#define D_STATE 16
#define DT_RANK 48
#define N_LAYERS 24
#define NCHUNK 16
#define CS (L_SEQ / NCHUNK)  // 64

typedef __attribute__((ext_vector_type(8))) short short8;
typedef __attribute__((ext_vector_type(4))) float f32x4;

__device__ inline void split1(float v, ushort& hi, ushort& lo) {
  unsigned b = __float_as_uint(v);
  hi = (ushort)(b >> 16);
  float lof = v - __uint_as_float(b & 0xFFFF0000u);
  lo = (ushort)(__float_as_uint(lof) >> 16);
}

__device__ inline void gload16(const void* g, void* l) {
  __builtin_amdgcn_global_load_lds(
      (const __attribute__((address_space(1))) void*)g,
      (__attribute__((address_space(3))) void*)l, 16, 0, 0);
}

// ---------------------------------------------------------------------------
// transpose + split: in [K][N] fp32 (layer l) -> hi/lo [N][Kp] bf16.
// rows k >= K zero-padded. grid (N/64, Kp/64, L) x 256.
__global__ __launch_bounds__(256) void tsplit_k(
    const float* __restrict__ in, ushort* __restrict__ hi,
    ushort* __restrict__ lo, int K, int N, int Kp) {
  __shared__ float tile[64][65];
  const int l = blockIdx.z;
  const float* src = in + (size_t)l * K * N;
  ushort* dh = hi + (size_t)l * N * Kp;
  ushort* dl = lo + (size_t)l * N * Kp;
  const int n0 = blockIdx.x * 64, k0 = blockIdx.y * 64;
  const int tx = threadIdx.x & 63, ty = threadIdx.x >> 6;
#pragma unroll
  for (int rr = 0; rr < 16; rr++) {
    int ky = rr * 4 + ty;
    int k = k0 + ky;
    tile[ky][tx] = (k < K) ? src[(size_t)k * N + n0 + tx] : 0.f;
  }
  __syncthreads();
#pragma unroll
  for (int rr = 0; rr < 16; rr++) {
    int ny = rr * 4 + ty;
    float v = tile[tx][ny];
    ushort h, s;
    split1(v, h, s);
    size_t o = (size_t)(n0 + ny) * Kp + k0 + tx;
    dh[o] = h;
    dl[o] = s;
  }
}

// ---------------------------------------------------------------------------
// split-bf16 3-pass MFMA GEMM, pre-split inputs, global_load_lds staging,
// XOR-swizzled LDS (pre-swizzled global source + swizzled ds_read; rule #21).
// A: hi/lo [M][lda] bf16, B: hi/lo [N][ldb] bf16 (transposed weights).
// C fp32 [M][ldc]. K % 32 == 0, M % 64 == 0, N % 64 == 0.
// block = 256 thr = 4 waves (2x2); tile 64x64, BK=32. LDS 16 KB.
// EPI: 0 = store, 1 = softplus(c + bias[n]), 2 = C += c
template <int EPI>
__global__ __launch_bounds__(256) void gemm_bf16s(
    const ushort* __restrict__ Ahi, const ushort* __restrict__ Alo, int lda,
    const ushort* __restrict__ Bhi, const ushort* __restrict__ Blo, int ldb,
    float* __restrict__ C, int ldc, int K, const float* __restrict__ bias) {
  // 256 rows x 32 bf16: [Ahi(64) | Alo(64) | Bhi(64) | Blo(64)]
  __shared__ ushort lds[256 * 32];

  const int tid = threadIdx.x;
  const int bm = blockIdx.y * 64;
  const int bn = blockIdx.x * 64;
  const int lane = tid & 63;
  const int wid = tid >> 6;
  const int wm = wid & 1, wn = wid >> 1;
  const int r = lane & 15, g = lane >> 4;
  const int segrow = lane >> 2;          // row within 16-row segment
  const int segch = lane & 3;            // 16B chunk within row

  f32x4 acc[2][2] = {};

  for (int k0 = 0; k0 < K; k0 += 32) {
    // ---- async global->LDS staging: 16 segments x 1KB, 4 per wave.
    // source chunk pre-swizzled so that swizzled read returns A[row][g].
#pragma unroll
    for (int i = 0; i < 4; i++) {
      int s = wid * 4 + i;                 // wave-uniform segment id
      int gr = s * 16 + segrow;            // 0..255 concat row
      int rt = gr & 63;                    // row within tile
      int ch = segch ^ ((rt >> 1) & 3);    // pre-swizzled source chunk
      const ushort* src;
      int row, ld;
      if (gr < 64) {
        src = Ahi; row = bm + rt; ld = lda;
      } else if (gr < 128) {
        src = Alo; row = bm + rt; ld = lda;
      } else if (gr < 192) {
        src = Bhi; row = bn + rt; ld = ldb;
      } else {
        src = Blo; row = bn + rt; ld = ldb;
      }
      gload16(src + (size_t)row * ld + k0 + ch * 8, &lds[s * 512]);
    }
    __syncthreads();  // drains vmcnt -> tiles ready

    short8 ahi[2], alo[2], bhi[2], blo[2];
#pragma unroll
    for (int m = 0; m < 2; m++) {
      int row = wm * 32 + m * 16 + r;
      int gg = g ^ ((row >> 1) & 3);       // swizzled read slot
      ahi[m] = *reinterpret_cast<short8*>(&lds[row * 32 + gg * 8]);
      alo[m] = *reinterpret_cast<short8*>(&lds[(64 + row) * 32 + gg * 8]);
    }
#pragma unroll
    for (int n = 0; n < 2; n++) {
      int row = wn * 32 + n * 16 + r;
      int gg = g ^ ((row >> 1) & 3);
      bhi[n] = *reinterpret_cast<short8*>(&lds[(128 + row) * 32 + gg * 8]);
      blo[n] = *reinterpret_cast<short8*>(&lds[(192 + row) * 32 + gg * 8]);
    }
#pragma unroll
    for (int m = 0; m < 2; m++)
#pragma unroll
      for (int n = 0; n < 2; n++) {
        acc[m][n] = __builtin_amdgcn_mfma_f32_16x16x32_bf16(
            ahi[m], bhi[n], acc[m][n], 0, 0, 0);
        acc[m][n] = __builtin_amdgcn_mfma_f32_16x16x32_bf16(
            ahi[m], blo[n], acc[m][n], 0, 0, 0);
        acc[m][n] = __builtin_amdgcn_mfma_f32_16x16x32_bf16(
            alo[m], bhi[n], acc[m][n], 0, 0, 0);
      }
    __syncthreads();  // reads done before next staging overwrites
  }

#pragma unroll
  for (int m = 0; m < 2; m++) {
#pragma unroll
    for (int n = 0; n < 2; n++) {
      int row0 = bm + wm * 32 + m * 16 + g * 4;
      int col = bn + wn * 32 + n * 16 + r;
#pragma unroll
      for (int j = 0; j < 4; j++) {
        size_t idx = (size_t)(row0 + j) * ldc + col;
        float v = acc[m][n][j];
        if (EPI == 0) {
          C[idx] = v;
        } else if (EPI == 1) {
          v += bias[col];
          C[idx] = (v > 20.f) ? v : log1pf(__expf(v));
        } else {
          C[idx] += v;
        }
      }
    }
  }
}

// ---------------------------------------------------------------------------
__global__ __launch_bounds__(256) void encode_k(
    const float* __restrict__ x, const float* __restrict__ w_enc,
    const float* __restrict__ b_enc, float* __restrict__ u) {
  int d = blockIdx.x * 256 + threadIdx.x;
  int t = blockIdx.y;
  const float4 xv = *(const float4*)(x + t * 4);
  float acc = b_enc[d];
  acc = fmaf(xv.x, w_enc[0 * D_MODEL + d], acc);
  acc = fmaf(xv.y, w_enc[1 * D_MODEL + d], acc);
  acc = fmaf(xv.z, w_enc[2 * D_MODEL + d], acc);
  acc = fmaf(xv.w, w_enc[3 * D_MODEL + d], acc);
  u[t * D_MODEL + d] = acc;
}

// ---------------------------------------------------------------------------
// rmsnorm with split-bf16 output planes
__global__ __launch_bounds__(256) void rmsnorm_split_k(
    const float* __restrict__ u, const float* __restrict__ w,
    ushort* __restrict__ hh, ushort* __restrict__ hl) {
  int t = blockIdx.x;
  const float* ur = u + t * D_MODEL;
  float ss = 0.f;
  for (int d = threadIdx.x; d < D_MODEL; d += 256) {
    float v = ur[d];
    ss = fmaf(v, v, ss);
  }
#pragma unroll
  for (int o = 1; o < 64; o <<= 1) ss += __shfl_xor(ss, o);
  __shared__ float red[4];
  int wid = threadIdx.x >> 6;
  if ((threadIdx.x & 63) == 0) red[wid] = ss;
  __syncthreads();
  float tot = red[0] + red[1] + red[2] + red[3];
  float rs = rsqrtf(tot / (float)D_MODEL + 1e-5f);
  for (int d = threadIdx.x; d < D_MODEL; d += 256) {
    float v = ur[d] * rs * w[d];
    ushort h, s;
    split1(v, h, s);
    hh[t * D_MODEL + d] = h;
    hl[t * D_MODEL + d] = s;
  }
}

// ---------------------------------------------------------------------------
// dbl GEMM (M=1024, N=80, K=1536) split-K partial kernel (fp32), with the
// causal depthwise conv (k=4) + bias + silu FUSED into A-staging.
// Each (t,c) element of xc is computed exactly once across the grid
// (k-segs partition c, m-tiles partition t) and written out for the scan.
#define DBL_NS 8
#define DBL_KSEG (D_INNER / DBL_NS)  // 192
__global__ __launch_bounds__(256) void gemm_dblconv_k(
    const float* __restrict__ xz, const float* __restrict__ cw,
    const float* __restrict__ cb, const float* __restrict__ B,
    float* __restrict__ P, float* __restrict__ xc) {
  __shared__ float As2[16][17];
  __shared__ float Bs2[16][80];
  const int tid = threadIdx.x;
  const int bm = blockIdx.y * 16;
  const int ks0 = blockIdx.x * DBL_KSEG;
  const int tx = tid % 16;
  const int ty = tid / 16;
  const int sm = tid / 16, sk = tid % 16;  // staging: (t row, c col)

  float acc[5] = {0.f, 0.f, 0.f, 0.f, 0.f};

  for (int k0 = ks0; k0 < ks0 + DBL_KSEG; k0 += 16) {
    {
      int t = bm + sm, c = k0 + sk;
      const float4 w = *(const float4*)(cw + c * 4);
      float a = cb[c];
      if (t >= 3) a = fmaf(xz[(size_t)(t - 3) * 2 * D_INNER + c], w.x, a);
      if (t >= 2) a = fmaf(xz[(size_t)(t - 2) * 2 * D_INNER + c], w.y, a);
      if (t >= 1) a = fmaf(xz[(size_t)(t - 1) * 2 * D_INNER + c], w.z, a);
      a = fmaf(xz[(size_t)t * 2 * D_INNER + c], w.w, a);
      float v = a / (1.f + __expf(-a));
      xc[(size_t)t * D_INNER + c] = v;
      As2[sk][sm] = v;
    }
    for (int i = tid; i < 16 * 80; i += 256) {
      int k = i / 80, n = i % 80;
      Bs2[k][n] = B[(size_t)(k0 + k) * 80 + n];
    }
    __syncthreads();
#pragma unroll
    for (int k = 0; k < 16; k++) {
      float ra = As2[k][ty];
#pragma unroll
      for (int j = 0; j < 5; j++) acc[j] = fmaf(ra, Bs2[k][tx * 5 + j], acc[j]);
    }
    __syncthreads();
  }

  float* p = P + ((size_t)blockIdx.x * L_SEQ + bm + ty) * 80 + tx * 5;
#pragma unroll
  for (int j = 0; j < 5; j++) p[j] = acc[j];
}

// reduce + emit dtA split planes [1024][64] (cols 48..63 zero)
__global__ __launch_bounds__(256) void dbl_reduce_k(
    const float* __restrict__ P, float* __restrict__ dbl,
    ushort* __restrict__ dah, ushort* __restrict__ dal) {
  int i = blockIdx.x * 256 + threadIdx.x;  // 0..81919
  float s = 0.f;
#pragma unroll
  for (int ks = 0; ks < DBL_NS; ks++) s += P[(size_t)ks * L_SEQ * 80 + i];
  dbl[i] = s;
  int rowi = i / 80, col = i % 80;
  if (col < DT_RANK) {
    ushort h, lo;
    split1(s, h, lo);
    dah[rowi * 64 + col] = h;
    dal[rowi * 64 + col] = lo;
  } else if (col >= 64) {  // cover pad cols 48..63
    dah[rowi * 64 + col - 16] = 0;
    dal[rowi * 64 + col - 16] = 0;
  }
}

// ---------------------------------------------------------------------------
// Chunked selective scan, NCHUNK=16 chunks of 64 steps. Phase 2 (chunk
// combine) is folded into scan3 (each thread combines its own <=15 pairs).
__global__ __launch_bounds__(256) void scan1_k(
    const float* __restrict__ dt, const float* __restrict__ xc,
    const float* __restrict__ dbl, const float* __restrict__ A_log,
    float* __restrict__ Pb, float* __restrict__ Eb) {
  __shared__ float s_dt[CS][16];
  __shared__ float s_xc[CS][16];
  __shared__ float s_b[CS][16];
  const int tid = threadIdx.x;
  const int s = tid & 15;
  const int cl = tid >> 4;
  const int c0 = blockIdx.y * 16;
  const int c = c0 + cl;
  const int t0 = blockIdx.x * CS;
  const float a = -__expf(A_log[c * D_STATE + s]);

  const int lc = tid & 15, lt = tid >> 4;
#pragma unroll
  for (int p = 0; p < CS / 16; p++) {
    int t = lt + p * 16;
    size_t gt = (size_t)(t0 + t);
    s_dt[t][lc] = dt[gt * D_INNER + c0 + lc];
    s_xc[t][lc] = xc[gt * D_INNER + c0 + lc];
    s_b[t][lc] = dbl[gt * 80 + DT_RANK + lc];
  }
  __syncthreads();

  float P = 1.f, h = 0.f;
  for (int t = 0; t < CS; t++) {
    float dtv = s_dt[t][cl];
    float dA = __expf(dtv * a);
    P *= dA;
    h = fmaf(dA, h, dtv * s_b[t][s] * s_xc[t][cl]);
  }
  int idx = blockIdx.x * (D_INNER * D_STATE) + c0 * D_STATE + tid;
  Pb[idx] = P;
  Eb[idx] = h;
}

// phase 3 (+ inline chunk combine) -> writes y as split bf16 planes
__global__ __launch_bounds__(256) void scan3_k(
    const float* __restrict__ dt, const float* __restrict__ xc,
    const float* __restrict__ dbl, const float* __restrict__ xz,
    const float* __restrict__ A_log, const float* __restrict__ D_skip,
    const float* __restrict__ Pb, const float* __restrict__ Eb,
    ushort* __restrict__ yh, ushort* __restrict__ yl) {
  __shared__ float s_dt[CS][16];
  __shared__ float s_xc[CS][16];
  __shared__ float s_z[CS][16];
  __shared__ float s_bc[CS][32];

  const int tid = threadIdx.x;
  const int s = tid & 15;
  const int cl = tid >> 4;
  const int c0 = blockIdx.y * 16;
  const int c = c0 + cl;
  const int t0 = blockIdx.x * CS;

  const float a = -__expf(A_log[c * D_STATE + s]);
  const float Dv = D_skip[c];

  const int lc = tid & 15, lt = tid >> 4;
  const int bj = tid & 31, bt = tid >> 5;
#pragma unroll
  for (int p = 0; p < CS / 16; p++) {
    int t = lt + p * 16;
    size_t gt = (size_t)(t0 + t);
    s_dt[t][lc] = dt[gt * D_INNER + c0 + lc];
    s_xc[t][lc] = xc[gt * D_INNER + c0 + lc];
    s_z[t][lc] = xz[gt * 2 * D_INNER + D_INNER + c0 + lc];
  }
#pragma unroll
  for (int p = 0; p < CS / 8; p++) {
    int t = bt + p * 8;
    s_bc[t][bj] = dbl[(size_t)(t0 + t) * 80 + DT_RANK + bj];
  }

  // inline chunk combine (replaces scan2): start state for this chunk.
  // fully unrolled, static indices (rule #20) -> stays in registers.
  float hst = 0.f;
  {
    const int nj = blockIdx.x;
    const int base = c0 * D_STATE + tid;
    float pj[NCHUNK - 1], ej[NCHUNK - 1];
#pragma unroll
    for (int jj = 0; jj < NCHUNK - 1; jj++) {
      if (jj < nj) {
        int o = jj * (D_INNER * D_STATE) + base;
        pj[jj] = Pb[o];
        ej[jj] = Eb[o];
      }
    }
#pragma unroll
    for (int jj = 0; jj < NCHUNK - 1; jj++)
      if (jj < nj) hst = fmaf(pj[jj], hst, ej[jj]);
  }
  __syncthreads();

  for (int t = 0; t < CS; t++) {
    float dtv = s_dt[t][cl];
    float xv = s_xc[t][cl];
    float Bv = s_bc[t][s];
    float Cv = s_bc[t][16 + s];
    float dA = __expf(dtv * a);
    hst = fmaf(dA, hst, dtv * Bv * xv);
    float p2 = hst * Cv;
    p2 += __shfl_xor(p2, 1);
    p2 += __shfl_xor(p2, 2);
    p2 += __shfl_xor(p2, 4);
    p2 += __shfl_xor(p2, 8);
    if (s == 0) {
      float zv = s_z[t][cl];
      float sz = zv / (1.f + __expf(-zv));
      float yv = (p2 + Dv * xv) * sz;
      ushort h, lo;
      split1(yv, h, lo);
      size_t o = (size_t)(t0 + t) * D_INNER + c;
      yh[o] = h;
      yl[o] = lo;
    }
  }
}

// ---------------------------------------------------------------------------
__global__ __launch_bounds__(256) void final_k(
    const float* __restrict__ u, const float* __restrict__ nfw,
    const float* __restrict__ fcw, const float* __restrict__ fcb,
    float* __restrict__ out) {
  const float* ur = u + (size_t)(L_SEQ - 1) * D_MODEL;
  float ss = 0.f;
  for (int d = threadIdx.x; d < D_MODEL; d += 256) {
    float v = ur[d];
    ss = fmaf(v, v, ss);
  }
#pragma unroll
  for (int o = 1; o < 64; o <<= 1) ss += __shfl_xor(ss, o);
  __shared__ float red[4];
  int wid = threadIdx.x >> 6;
  if ((threadIdx.x & 63) == 0) red[wid] = ss;
  __syncthreads();
  float tot = red[0] + red[1] + red[2] + red[3];
  float rs = rsqrtf(tot / (float)D_MODEL + 1e-5f);
  float a0 = 0.f, a1 = 0.f;
  for (int d = threadIdx.x; d < D_MODEL; d += 256) {
    float hn = ur[d] * rs * nfw[d];
    a0 = fmaf(hn, fcw[d * 2 + 0], a0);
    a1 = fmaf(hn, fcw[d * 2 + 1], a1);
  }
#pragma unroll
  for (int o = 1; o < 64; o <<= 1) {
    a0 += __shfl_xor(a0, o);
    a1 += __shfl_xor(a1, o);
  }
  __shared__ float r0[4], r1[4];
  if ((threadIdx.x & 63) == 0) {
    r0[wid] = a0;
    r1[wid] = a1;
  }
  __syncthreads();
  if (threadIdx.x == 0) out[0] = r0[0] + r0[1] + r0[2] + r0[3] + fcb[0];
  if (threadIdx.x == 1) out[1] = r1[0] + r1[1] + r1[2] + r1[3] + fcb[1];
}

// ---------------------------------------------------------------------------
extern "C" void kernel_launch(void* const* d_in, const int* in_sizes, int n_in,
                              void* d_out, int out_size, void* d_ws,
                              size_t ws_size, hipStream_t stream) {
  const float* x      = (const float*)d_in[0];
  const float* w_enc  = (const float*)d_in[1];
  const float* b_enc  = (const float*)d_in[2];
  const float* norm_w = (const float*)d_in[3];
  const float* in_w   = (const float*)d_in[4];
  const float* conv_w = (const float*)d_in[5];
  const float* conv_b = (const float*)d_in[6];
  const float* xp_w   = (const float*)d_in[7];
  const float* dt_w   = (const float*)d_in[8];
  const float* dt_b   = (const float*)d_in[9];
  const float* A_log  = (const float*)d_in[10];
  const float* D_skip = (const float*)d_in[11];
  const float* out_w  = (const float*)d_in[12];
  const float* nf_w   = (const float*)d_in[13];
  const float* fc_w   = (const float*)d_in[14];
  const float* fc_b   = (const float*)d_in[15];
  float* out = (float*)d_out;

  // ---- fp32 workspace
  float* u   = (float*)d_ws;
  float* xzb = u   + (size_t)L_SEQ * D_MODEL;
  float* xcb = xzb + (size_t)L_SEQ * 2 * D_INNER;
  float* dbl = xcb + (size_t)L_SEQ * D_INNER;
  float* dtb = dbl + (size_t)L_SEQ * 80;
  float* yb  = dtb + (size_t)L_SEQ * D_INNER;   // dbl split-K partials
  float* Pb  = yb  + (size_t)L_SEQ * D_INNER;
  float* Eb  = Pb  + (size_t)NCHUNK * D_INNER * D_STATE;
  float* fend = Eb + (size_t)NCHUNK * D_INNER * D_STATE;

  // ---- bf16 plane workspace (activations + repacked weights)
  ushort* hh  = (ushort*)fend;                  // [1024][768]
  ushort* hl  = hh + (size_t)L_SEQ * D_MODEL;
  ushort* dah = hl + (size_t)L_SEQ * D_MODEL;   // [1024][64]
  ushort* dal = dah + (size_t)L_SEQ * 64;
  ushort* yh  = dal + (size_t)L_SEQ * 64;       // [1024][1536]
  ushort* yl  = yh + (size_t)L_SEQ * D_INNER;
  ushort* wxh = yl + (size_t)L_SEQ * D_INNER;   // in_w^T  [24][3072][768]
  ushort* wxl = wxh + (size_t)N_LAYERS * 2 * D_INNER * D_MODEL;
  ushort* wdh = wxl + (size_t)N_LAYERS * 2 * D_INNER * D_MODEL;  // dt_w^T [24][1536][64]
  ushort* wdl = wdh + (size_t)N_LAYERS * D_INNER * 64;
  ushort* woh = wdl + (size_t)N_LAYERS * D_INNER * 64;  // out_w^T [24][768][1536]
  ushort* wol = woh + (size_t)N_LAYERS * D_MODEL * D_INNER;

  // ---- one-time per call: weight repack (transpose + bf16 split)
  tsplit_k<<<dim3(2 * D_INNER / 64, D_MODEL / 64, N_LAYERS), 256, 0, stream>>>(
      in_w, wxh, wxl, D_MODEL, 2 * D_INNER, D_MODEL);
  tsplit_k<<<dim3(D_INNER / 64, 1, N_LAYERS), 256, 0, stream>>>(
      dt_w, wdh, wdl, DT_RANK, D_INNER, 64);
  tsplit_k<<<dim3(D_MODEL / 64, D_INNER / 64, N_LAYERS), 256, 0, stream>>>(
      out_w, woh, wol, D_INNER, D_MODEL, D_INNER);

  encode_k<<<dim3(3, L_SEQ), 256, 0, stream>>>(x, w_enc, b_enc, u);

  for (int l = 0; l < N_LAYERS; l++) {
    const float* cw_l    = conv_w + (size_t)l * D_INNER * 4;
    const float* cb_l    = conv_b + (size_t)l * D_INNER;
    const float* xp_w_l  = xp_w  + (size_t)l * D_INNER * 80;
    const float* dt_b_l  = dt_b  + (size_t)l * D_INNER;
    const float* A_log_l = A_log + (size_t)l * D_INNER * D_STATE;
    const float* D_l     = D_skip + (size_t)l * D_INNER;
    const ushort* wxh_l = wxh + (size_t)l * 2 * D_INNER * D_MODEL;
    const ushort* wxl_l = wxl + (size_t)l * 2 * D_INNER * D_MODEL;
    const ushort* wdh_l = wdh + (size_t)l * D_INNER * 64;
    const ushort* wdl_l = wdl + (size_t)l * D_INNER * 64;
    const ushort* woh_l = woh + (size_t)l * D_MODEL * D_INNER;
    const ushort* wol_l = wol + (size_t)l * D_MODEL * D_INNER;

    // h(hi/lo) = rmsnorm(u) * norm_w
    rmsnorm_split_k<<<L_SEQ, 256, 0, stream>>>(
        u, norm_w + (size_t)l * D_MODEL, hh, hl);
    // xz = h @ in_w : M=1024 N=3072 K=768 (768 blocks)
    gemm_bf16s<0><<<dim3(2 * D_INNER / 64, L_SEQ / 64), 256, 0, stream>>>(
        hh, hl, D_MODEL, wxh_l, wxl_l, D_MODEL, xzb, 2 * D_INNER, D_MODEL,
        nullptr);
    // xc = silu(conv(xpart)+cb) fused into dbl split-K GEMM (writes xcb too)
    gemm_dblconv_k<<<dim3(DBL_NS, L_SEQ / 16), 256, 0, stream>>>(
        xzb, cw_l, cb_l, xp_w_l, yb, xcb);
    dbl_reduce_k<<<(L_SEQ * 80) / 256, 256, 0, stream>>>(yb, dbl, dah, dal);
    // dt = softplus(dbl[:, :48] @ dt_w + dt_b) : K=48 padded to 64 (384 blk)
    gemm_bf16s<1><<<dim3(D_INNER / 64, L_SEQ / 64), 256, 0, stream>>>(
        dah, dal, 64, wdh_l, wdl_l, 64, dtb, D_INNER, 64, dt_b_l);
    // chunked selective scan + skip + silu(z) gate -> y (split planes)
    scan1_k<<<dim3(NCHUNK, D_INNER / 16), 256, 0, stream>>>(
        dtb, xcb, dbl, A_log_l, Pb, Eb);
    scan3_k<<<dim3(NCHUNK, D_INNER / 16), 256, 0, stream>>>(
        dtb, xcb, dbl, xzb, A_log_l, D_l, Pb, Eb, yh, yl);
    // u += y @ out_w : M=1024 N=768 K=1536 (192 blocks)
    gemm_bf16s<2><<<dim3(D_MODEL / 64, L_SEQ / 64), 256, 0, stream>>>(
        yh, yl, D_INNER, woh_l, wol_l, D_INNER, u, D_MODEL, D_INNER, nullptr);
  }

  final_k<<<1, 256, 0, stream>>>(u, nf_w, fc_w, fc_b, out);
}

// Round 8
// 3481.184 us; speedup vs baseline: 1.5489x; 1.2377x over previous
//
#include <hip/hip_runtime.h>
#include <hip/hip_bf16.h>

#define L_SEQ 1024
#define D_MODEL 768
#define D_INNER 1536
#define D_STATE 16
#define DT_RANK 48
#define N_LAYERS 24
#define NCHUNK 16
#define CS (L_SEQ / NCHUNK)  // 64

typedef __attribute__((ext_vector_type(8))) short short8;
typedef __attribute__((ext_vector_type(4))) float f32x4;

// fp32 -> bf16 round-to-nearest-even (unbiased; halves truncation error)
__device__ inline ushort rtn1(float v) {
  unsigned b = __float_as_uint(v);
  return (ushort)((b + 0x7FFF + ((b >> 16) & 1)) >> 16);
}

__device__ inline void gload16(const void* g, void* l) {
  __builtin_amdgcn_global_load_lds(
      (const __attribute__((address_space(1))) void*)g,
      (__attribute__((address_space(3))) void*)l, 16, 0, 0);
}

// ---------------------------------------------------------------------------
// transpose + bf16(RTN): in [K][N] fp32 (layer l) -> [N][Kp] bf16.
// rows k >= K zero-padded. grid (N/64, Kp/64, L) x 256.
__global__ __launch_bounds__(256) void tsplit_k(
    const float* __restrict__ in, ushort* __restrict__ hi, int K, int N,
    int Kp) {
  __shared__ float tile[64][65];
  const int l = blockIdx.z;
  const float* src = in + (size_t)l * K * N;
  ushort* dh = hi + (size_t)l * N * Kp;
  const int n0 = blockIdx.x * 64, k0 = blockIdx.y * 64;
  const int tx = threadIdx.x & 63, ty = threadIdx.x >> 6;
#pragma unroll
  for (int rr = 0; rr < 16; rr++) {
    int ky = rr * 4 + ty;
    int k = k0 + ky;
    tile[ky][tx] = (k < K) ? src[(size_t)k * N + n0 + tx] : 0.f;
  }
  __syncthreads();
#pragma unroll
  for (int rr = 0; rr < 16; rr++) {
    int ny = rr * 4 + ty;
    dh[(size_t)(n0 + ny) * Kp + k0 + tx] = rtn1(tile[tx][ny]);
  }
}

// ---------------------------------------------------------------------------
// 1-pass bf16 MFMA GEMM, global_load_lds staging, both-sides XOR swizzle.
// A [M][lda] bf16, B [N][ldb] bf16 (transposed weights). C fp32 [M][ldc].
// K % 32 == 0, M % 64 == 0, N % 64 == 0. block = 256 thr = 4 waves (2x2);
// tile 64x64, BK=32, LDS 8 KB. gridDim.z slices K (split-K partial outputs:
// caller passes C sized [z][M][ldc] and reduces).
// EPI: 0 = store, 1 = softplus(c + bias[n]), 2 = C += c
template <int EPI>
__global__ __launch_bounds__(256) void gemm_bf16(
    const ushort* __restrict__ A, int lda, const ushort* __restrict__ B,
    int ldb, float* __restrict__ C, int ldc, int K,
    const float* __restrict__ bias) {
  // 128 rows x 32 bf16: [A(64) | B(64)]
  __shared__ ushort lds[128 * 32];

  const int tid = threadIdx.x;
  const int bm = blockIdx.y * 64;
  const int bn = blockIdx.x * 64;
  const int kz0 = blockIdx.z * K;     // K-slice origin (split-K)
  const int lane = tid & 63;
  const int wid = tid >> 6;
  const int wm = wid & 1, wn = wid >> 1;
  const int r = lane & 15, g = lane >> 4;
  const int segrow = lane >> 2;       // row within 16-row segment
  const int segch = lane & 3;         // 16B chunk within row

  f32x4 acc[2][2] = {};

  for (int k0 = kz0; k0 < kz0 + K; k0 += 32) {
    // ---- async global->LDS: 8 segments x 1KB, 2 per wave.
#pragma unroll
    for (int i = 0; i < 2; i++) {
      int s = wid * 2 + i;
      int gr = s * 16 + segrow;          // 0..127 concat row
      int rt = gr & 63;
      int ch = segch ^ ((rt >> 1) & 3);  // pre-swizzled source chunk
      const ushort* src = (gr < 64) ? A : B;
      int row = ((gr < 64) ? bm : bn) + rt;
      int ld = (gr < 64) ? lda : ldb;
      gload16(src + (size_t)row * ld + k0 + ch * 8, &lds[s * 512]);
    }
    __syncthreads();  // drains vmcnt -> tiles ready

    short8 af[2], bf[2];
#pragma unroll
    for (int m = 0; m < 2; m++) {
      int row = wm * 32 + m * 16 + r;
      int gg = g ^ ((row >> 1) & 3);
      af[m] = *reinterpret_cast<short8*>(&lds[row * 32 + gg * 8]);
    }
#pragma unroll
    for (int n = 0; n < 2; n++) {
      int row = wn * 32 + n * 16 + r;
      int gg = g ^ ((row >> 1) & 3);
      bf[n] = *reinterpret_cast<short8*>(&lds[(64 + row) * 32 + gg * 8]);
    }
#pragma unroll
    for (int m = 0; m < 2; m++)
#pragma unroll
      for (int n = 0; n < 2; n++)
        acc[m][n] = __builtin_amdgcn_mfma_f32_16x16x32_bf16(
            af[m], bf[n], acc[m][n], 0, 0, 0);
    __syncthreads();
  }

  float* Cz = C + (size_t)blockIdx.z * gridDim.y * 64 * ldc;
#pragma unroll
  for (int m = 0; m < 2; m++) {
#pragma unroll
    for (int n = 0; n < 2; n++) {
      int row0 = bm + wm * 32 + m * 16 + g * 4;
      int col = bn + wn * 32 + n * 16 + r;
#pragma unroll
      for (int j = 0; j < 4; j++) {
        size_t idx = (size_t)(row0 + j) * ldc + col;
        float v = acc[m][n][j];
        if (EPI == 0) {
          Cz[idx] = v;
        } else if (EPI == 1) {
          v += bias[col];
          Cz[idx] = (v > 20.f) ? v : log1pf(__expf(v));
        } else {
          Cz[idx] += v;
        }
      }
    }
  }
}

// u += P0 + P1 (split-K reduce for out-proj). grid 768 x 256, float4.
__global__ __launch_bounds__(256) void addu_k(const float* __restrict__ P,
                                              float* __restrict__ u) {
  int i = blockIdx.x * 256 + threadIdx.x;
  float4 a = *(const float4*)(P + (size_t)i * 4);
  float4 b = *(const float4*)(P + (size_t)(L_SEQ * D_MODEL) + (size_t)i * 4);
  float4 v = *(float4*)(u + (size_t)i * 4);
  v.x += a.x + b.x; v.y += a.y + b.y; v.z += a.z + b.z; v.w += a.w + b.w;
  *(float4*)(u + (size_t)i * 4) = v;
}

// ---------------------------------------------------------------------------
__global__ __launch_bounds__(256) void encode_k(
    const float* __restrict__ x, const float* __restrict__ w_enc,
    const float* __restrict__ b_enc, float* __restrict__ u) {
  int d = blockIdx.x * 256 + threadIdx.x;
  int t = blockIdx.y;
  const float4 xv = *(const float4*)(x + t * 4);
  float acc = b_enc[d];
  acc = fmaf(xv.x, w_enc[0 * D_MODEL + d], acc);
  acc = fmaf(xv.y, w_enc[1 * D_MODEL + d], acc);
  acc = fmaf(xv.z, w_enc[2 * D_MODEL + d], acc);
  acc = fmaf(xv.w, w_enc[3 * D_MODEL + d], acc);
  u[t * D_MODEL + d] = acc;
}

// ---------------------------------------------------------------------------
// rmsnorm -> bf16 (RTN) output
__global__ __launch_bounds__(256) void rmsnorm_b_k(
    const float* __restrict__ u, const float* __restrict__ w,
    ushort* __restrict__ hb) {
  int t = blockIdx.x;
  const float* ur = u + t * D_MODEL;
  float ss = 0.f;
  for (int d = threadIdx.x; d < D_MODEL; d += 256) {
    float v = ur[d];
    ss = fmaf(v, v, ss);
  }
#pragma unroll
  for (int o = 1; o < 64; o <<= 1) ss += __shfl_xor(ss, o);
  __shared__ float red[4];
  int wid = threadIdx.x >> 6;
  if ((threadIdx.x & 63) == 0) red[wid] = ss;
  __syncthreads();
  float tot = red[0] + red[1] + red[2] + red[3];
  float rs = rsqrtf(tot / (float)D_MODEL + 1e-5f);
  for (int d = threadIdx.x; d < D_MODEL; d += 256) {
    hb[t * D_MODEL + d] = rtn1(ur[d] * rs * w[d]);
  }
}

// ---------------------------------------------------------------------------
// dbl GEMM (M=1024, N=80, K=1536) split-K fp32 partials, conv+silu fused
// into A-staging (writes xc exactly once per (t,c)).
#define DBL_NS 8
#define DBL_KSEG (D_INNER / DBL_NS)  // 192
__global__ __launch_bounds__(256) void gemm_dblconv_k(
    const float* __restrict__ xz, const float* __restrict__ cw,
    const float* __restrict__ cb, const float* __restrict__ B,
    float* __restrict__ P, float* __restrict__ xc) {
  __shared__ float As2[16][17];
  __shared__ float Bs2[16][80];
  const int tid = threadIdx.x;
  const int bm = blockIdx.y * 16;
  const int ks0 = blockIdx.x * DBL_KSEG;
  const int tx = tid % 16;
  const int ty = tid / 16;
  const int sm = tid / 16, sk = tid % 16;

  float acc[5] = {0.f, 0.f, 0.f, 0.f, 0.f};

  for (int k0 = ks0; k0 < ks0 + DBL_KSEG; k0 += 16) {
    {
      int t = bm + sm, c = k0 + sk;
      const float4 w = *(const float4*)(cw + c * 4);
      float a = cb[c];
      if (t >= 3) a = fmaf(xz[(size_t)(t - 3) * 2 * D_INNER + c], w.x, a);
      if (t >= 2) a = fmaf(xz[(size_t)(t - 2) * 2 * D_INNER + c], w.y, a);
      if (t >= 1) a = fmaf(xz[(size_t)(t - 1) * 2 * D_INNER + c], w.z, a);
      a = fmaf(xz[(size_t)t * 2 * D_INNER + c], w.w, a);
      float v = a / (1.f + __expf(-a));
      xc[(size_t)t * D_INNER + c] = v;
      As2[sk][sm] = v;
    }
    for (int i = tid; i < 16 * 80; i += 256) {
      int k = i / 80, n = i % 80;
      Bs2[k][n] = B[(size_t)(k0 + k) * 80 + n];
    }
    __syncthreads();
#pragma unroll
    for (int k = 0; k < 16; k++) {
      float ra = As2[k][ty];
#pragma unroll
      for (int j = 0; j < 5; j++) acc[j] = fmaf(ra, Bs2[k][tx * 5 + j], acc[j]);
    }
    __syncthreads();
  }

  float* p = P + ((size_t)blockIdx.x * L_SEQ + bm + ty) * 80 + tx * 5;
#pragma unroll
  for (int j = 0; j < 5; j++) p[j] = acc[j];
}

// reduce + emit dt-GEMM A operand [1024][64] bf16 (cols 48..63 zero)
__global__ __launch_bounds__(256) void dbl_reduce_k(
    const float* __restrict__ P, float* __restrict__ dbl,
    ushort* __restrict__ dab) {
  int i = blockIdx.x * 256 + threadIdx.x;  // 0..81919
  float s = 0.f;
#pragma unroll
  for (int ks = 0; ks < DBL_NS; ks++) s += P[(size_t)ks * L_SEQ * 80 + i];
  dbl[i] = s;
  int rowi = i / 80, col = i % 80;
  if (col < DT_RANK) {
    dab[rowi * 64 + col] = rtn1(s);
  } else if (col >= 64) {  // cover pad cols 48..63
    dab[rowi * 64 + col - 16] = 0;
  }
}

// ---------------------------------------------------------------------------
// Chunked selective scan, NCHUNK=16 chunks of 64 steps; chunk combine
// folded into scan3.
__global__ __launch_bounds__(256) void scan1_k(
    const float* __restrict__ dt, const float* __restrict__ xc,
    const float* __restrict__ dbl, const float* __restrict__ A_log,
    float* __restrict__ Pb, float* __restrict__ Eb) {
  __shared__ float s_dt[CS][16];
  __shared__ float s_xc[CS][16];
  __shared__ float s_b[CS][16];
  const int tid = threadIdx.x;
  const int s = tid & 15;
  const int cl = tid >> 4;
  const int c0 = blockIdx.y * 16;
  const int c = c0 + cl;
  const int t0 = blockIdx.x * CS;
  const float a = -__expf(A_log[c * D_STATE + s]);

  const int lc = tid & 15, lt = tid >> 4;
#pragma unroll
  for (int p = 0; p < CS / 16; p++) {
    int t = lt + p * 16;
    size_t gt = (size_t)(t0 + t);
    s_dt[t][lc] = dt[gt * D_INNER + c0 + lc];
    s_xc[t][lc] = xc[gt * D_INNER + c0 + lc];
    s_b[t][lc] = dbl[gt * 80 + DT_RANK + lc];
  }
  __syncthreads();

  float P = 1.f, h = 0.f;
  for (int t = 0; t < CS; t++) {
    float dtv = s_dt[t][cl];
    float dA = __expf(dtv * a);
    P *= dA;
    h = fmaf(dA, h, dtv * s_b[t][s] * s_xc[t][cl]);
  }
  int idx = blockIdx.x * (D_INNER * D_STATE) + c0 * D_STATE + tid;
  Pb[idx] = P;
  Eb[idx] = h;
}

// phase 3 (+ inline chunk combine) -> y bf16 (RTN)
__global__ __launch_bounds__(256) void scan3_k(
    const float* __restrict__ dt, const float* __restrict__ xc,
    const float* __restrict__ dbl, const float* __restrict__ xz,
    const float* __restrict__ A_log, const float* __restrict__ D_skip,
    const float* __restrict__ Pb, const float* __restrict__ Eb,
    ushort* __restrict__ yb16) {
  __shared__ float s_dt[CS][16];
  __shared__ float s_xc[CS][16];
  __shared__ float s_z[CS][16];
  __shared__ float s_bc[CS][32];

  const int tid = threadIdx.x;
  const int s = tid & 15;
  const int cl = tid >> 4;
  const int c0 = blockIdx.y * 16;
  const int c = c0 + cl;
  const int t0 = blockIdx.x * CS;

  const float a = -__expf(A_log[c * D_STATE + s]);
  const float Dv = D_skip[c];

  const int lc = tid & 15, lt = tid >> 4;
  const int bj = tid & 31, bt = tid >> 5;
#pragma unroll
  for (int p = 0; p < CS / 16; p++) {
    int t = lt + p * 16;
    size_t gt = (size_t)(t0 + t);
    s_dt[t][lc] = dt[gt * D_INNER + c0 + lc];
    s_xc[t][lc] = xc[gt * D_INNER + c0 + lc];
    s_z[t][lc] = xz[gt * 2 * D_INNER + D_INNER + c0 + lc];
  }
#pragma unroll
  for (int p = 0; p < CS / 8; p++) {
    int t = bt + p * 8;
    s_bc[t][bj] = dbl[(size_t)(t0 + t) * 80 + DT_RANK + bj];
  }

  // inline chunk combine: start state for this chunk (static indices)
  float hst = 0.f;
  {
    const int nj = blockIdx.x;
    const int base = c0 * D_STATE + tid;
    float pj[NCHUNK - 1], ej[NCHUNK - 1];
#pragma unroll
    for (int jj = 0; jj < NCHUNK - 1; jj++) {
      if (jj < nj) {
        int o = jj * (D_INNER * D_STATE) + base;
        pj[jj] = Pb[o];
        ej[jj] = Eb[o];
      }
    }
#pragma unroll
    for (int jj = 0; jj < NCHUNK - 1; jj++)
      if (jj < nj) hst = fmaf(pj[jj], hst, ej[jj]);
  }
  __syncthreads();

  for (int t = 0; t < CS; t++) {
    float dtv = s_dt[t][cl];
    float xv = s_xc[t][cl];
    float Bv = s_bc[t][s];
    float Cv = s_bc[t][16 + s];
    float dA = __expf(dtv * a);
    hst = fmaf(dA, hst, dtv * Bv * xv);
    float p2 = hst * Cv;
    p2 += __shfl_xor(p2, 1);
    p2 += __shfl_xor(p2, 2);
    p2 += __shfl_xor(p2, 4);
    p2 += __shfl_xor(p2, 8);
    if (s == 0) {
      float zv = s_z[t][cl];
      float sz = zv / (1.f + __expf(-zv));
      yb16[(size_t)(t0 + t) * D_INNER + c] = rtn1((p2 + Dv * xv) * sz);
    }
  }
}

// ---------------------------------------------------------------------------
__global__ __launch_bounds__(256) void final_k(
    const float* __restrict__ u, const float* __restrict__ nfw,
    const float* __restrict__ fcw, const float* __restrict__ fcb,
    float* __restrict__ out) {
  const float* ur = u + (size_t)(L_SEQ - 1) * D_MODEL;
  float ss = 0.f;
  for (int d = threadIdx.x; d < D_MODEL; d += 256) {
    float v = ur[d];
    ss = fmaf(v, v, ss);
  }
#pragma unroll
  for (int o = 1; o < 64; o <<= 1) ss += __shfl_xor(ss, o);
  __shared__ float red[4];
  int wid = threadIdx.x >> 6;
  if ((threadIdx.x & 63) == 0) red[wid] = ss;
  __syncthreads();
  float tot = red[0] + red[1] + red[2] + red[3];
  float rs = rsqrtf(tot / (float)D_MODEL + 1e-5f);
  float a0 = 0.f, a1 = 0.f;
  for (int d = threadIdx.x; d < D_MODEL; d += 256) {
    float hn = ur[d] * rs * nfw[d];
    a0 = fmaf(hn, fcw[d * 2 + 0], a0);
    a1 = fmaf(hn, fcw[d * 2 + 1], a1);
  }
#pragma unroll
  for (int o = 1; o < 64; o <<= 1) {
    a0 += __shfl_xor(a0, o);
    a1 += __shfl_xor(a1, o);
  }
  __shared__ float r0[4], r1[4];
  if ((threadIdx.x & 63) == 0) {
    r0[wid] = a0;
    r1[wid] = a1;
  }
  __syncthreads();
  if (threadIdx.x == 0) out[0] = r0[0] + r0[1] + r0[2] + r0[3] + fcb[0];
  if (threadIdx.x == 1) out[1] = r1[0] + r1[1] + r1[2] + r1[3] + fcb[1];
}

// ---------------------------------------------------------------------------
extern "C" void kernel_launch(void* const* d_in, const int* in_sizes, int n_in,
                              void* d_out, int out_size, void* d_ws,
                              size_t ws_size, hipStream_t stream) {
  const float* x      = (const float*)d_in[0];
  const float* w_enc  = (const float*)d_in[1];
  const float* b_enc  = (const float*)d_in[2];
  const float* norm_w = (const float*)d_in[3];
  const float* in_w   = (const float*)d_in[4];
  const float* conv_w = (const float*)d_in[5];
  const float* conv_b = (const float*)d_in[6];
  const float* xp_w   = (const float*)d_in[7];
  const float* dt_w   = (const float*)d_in[8];
  const float* dt_b   = (const float*)d_in[9];
  const float* A_log  = (const float*)d_in[10];
  const float* D_skip = (const float*)d_in[11];
  const float* out_w  = (const float*)d_in[12];
  const float* nf_w   = (const float*)d_in[13];
  const float* fc_w   = (const float*)d_in[14];
  const float* fc_b   = (const float*)d_in[15];
  float* out = (float*)d_out;

  // ---- fp32 workspace
  float* u   = (float*)d_ws;
  float* xzb = u   + (size_t)L_SEQ * D_MODEL;
  float* xcb = xzb + (size_t)L_SEQ * 2 * D_INNER;
  float* dbl = xcb + (size_t)L_SEQ * D_INNER;
  float* dtb = dbl + (size_t)L_SEQ * 80;
  float* yb  = dtb + (size_t)L_SEQ * D_INNER;   // dbl split-K partials
  float* Po  = yb  + (size_t)L_SEQ * 80 * DBL_NS;  // out split-K partials x2
  float* Pb  = Po  + (size_t)2 * L_SEQ * D_MODEL;
  float* Eb  = Pb  + (size_t)NCHUNK * D_INNER * D_STATE;
  float* fend = Eb + (size_t)NCHUNK * D_INNER * D_STATE;

  // ---- bf16 workspace (activations + repacked weights)
  ushort* hb   = (ushort*)fend;                 // [1024][768]
  ushort* dab  = hb + (size_t)L_SEQ * D_MODEL;  // [1024][64]
  ushort* yb16 = dab + (size_t)L_SEQ * 64;      // [1024][1536]
  ushort* wxT  = yb16 + (size_t)L_SEQ * D_INNER;  // in_w^T  [24][3072][768]
  ushort* wdT  = wxT + (size_t)N_LAYERS * 2 * D_INNER * D_MODEL;  // [24][1536][64]
  ushort* woT  = wdT + (size_t)N_LAYERS * D_INNER * 64;  // [24][768][1536]

  // ---- one-time per call: weight repack (transpose + bf16 RTN)
  tsplit_k<<<dim3(2 * D_INNER / 64, D_MODEL / 64, N_LAYERS), 256, 0, stream>>>(
      in_w, wxT, D_MODEL, 2 * D_INNER, D_MODEL);
  tsplit_k<<<dim3(D_INNER / 64, 1, N_LAYERS), 256, 0, stream>>>(
      dt_w, wdT, DT_RANK, D_INNER, 64);
  tsplit_k<<<dim3(D_MODEL / 64, D_INNER / 64, N_LAYERS), 256, 0, stream>>>(
      out_w, woT, D_INNER, D_MODEL, D_INNER);

  encode_k<<<dim3(3, L_SEQ), 256, 0, stream>>>(x, w_enc, b_enc, u);

  for (int l = 0; l < N_LAYERS; l++) {
    const float* cw_l    = conv_w + (size_t)l * D_INNER * 4;
    const float* cb_l    = conv_b + (size_t)l * D_INNER;
    const float* xp_w_l  = xp_w  + (size_t)l * D_INNER * 80;
    const float* dt_b_l  = dt_b  + (size_t)l * D_INNER;
    const float* A_log_l = A_log + (size_t)l * D_INNER * D_STATE;
    const float* D_l     = D_skip + (size_t)l * D_INNER;
    const ushort* wxT_l = wxT + (size_t)l * 2 * D_INNER * D_MODEL;
    const ushort* wdT_l = wdT + (size_t)l * D_INNER * 64;
    const ushort* woT_l = woT + (size_t)l * D_MODEL * D_INNER;

    // h = bf16(rmsnorm(u) * norm_w)
    rmsnorm_b_k<<<L_SEQ, 256, 0, stream>>>(
        u, norm_w + (size_t)l * D_MODEL, hb);
    // xz = h @ in_w : M=1024 N=3072 K=768 (768 blocks)
    gemm_bf16<0><<<dim3(2 * D_INNER / 64, L_SEQ / 64), 256, 0, stream>>>(
        hb, D_MODEL, wxT_l, D_MODEL, xzb, 2 * D_INNER, D_MODEL, nullptr);
    // xc = silu(conv(xpart)+cb) fused into dbl split-K GEMM (writes xcb too)
    gemm_dblconv_k<<<dim3(DBL_NS, L_SEQ / 16), 256, 0, stream>>>(
        xzb, cw_l, cb_l, xp_w_l, yb, xcb);
    dbl_reduce_k<<<(L_SEQ * 80) / 256, 256, 0, stream>>>(yb, dbl, dab);
    // dt = softplus(dbl[:, :48] @ dt_w + dt_b) : K=48 padded to 64 (384 blk)
    gemm_bf16<1><<<dim3(D_INNER / 64, L_SEQ / 64), 256, 0, stream>>>(
        dab, 64, wdT_l, 64, dtb, D_INNER, 64, dt_b_l);
    // chunked selective scan + skip + silu(z) gate -> y bf16
    scan1_k<<<dim3(NCHUNK, D_INNER / 16), 256, 0, stream>>>(
        dtb, xcb, dbl, A_log_l, Pb, Eb);
    scan3_k<<<dim3(NCHUNK, D_INNER / 16), 256, 0, stream>>>(
        dtb, xcb, dbl, xzb, A_log_l, D_l, Pb, Eb, yb16);
    // u += y @ out_w : M=1024 N=768 K=1536, split-K x2 (384 blocks, 1 launch)
    gemm_bf16<0><<<dim3(D_MODEL / 64, L_SEQ / 64, 2), 256, 0, stream>>>(
        yb16, D_INNER, woT_l, D_INNER, Po, D_MODEL, D_INNER / 2, nullptr);
    addu_k<<<(L_SEQ * D_MODEL) / 1024, 256, 0, stream>>>(Po, u);
  }

  final_k<<<1, 256, 0, stream>>>(u, nf_w, fc_w, fc_b, out);
}